// Round 4
// baseline (192.053 us; speedup 1.0000x reference)
//
#include <hip/hip_runtime.h>
#include <stdint.h>
#include <stddef.h>

// GA3 conv2d == one dense 3x3 conv with sign-permuted weights:
//   out[b, c*8+m, h, w] = bias_eff[c*8+m]
//     + sum_{cin,k,kh,kw} s(m,k) * W[j(m,k),c,cin,kh,kw] * x[b, cin*8+k, h+kh-1, w+kw-1]
// bf16 MFMA implicit GEMM over 9 taps (K=128 each).
// R2: latency/residency fix. Grid 512 = exactly 2 blocks/CU (all resident at t=0,
// no ramp/tail); each block does two h-tiles with T14 cross-tile register prefetch
// (tile-1 x-halo loads issued before tile-0 compute, written to LDS after).
// border_kernel merged into prep_kernel (one fewer launch).
// Carried from R1: XOR-swizzled lds_x, B-frags direct from L2-resident vt,
// border-zero instead of 34.6MB memset.

typedef __attribute__((ext_vector_type(8))) short short8;   // 8 x bf16 (4 VGPRs)
typedef __attribute__((ext_vector_type(4))) float f32x4;    // MFMA accumulator

// j(m,k) and s(m,k): unique j with S[m,j,k]!=0, transcribed from _TERMS.
__device__ __constant__ int c_J[64] = {
  0,1,2,3,4,5,6,7,
  1,0,4,6,2,7,3,5,
  2,4,0,5,1,3,7,6,
  3,6,5,0,7,2,1,4,
  4,2,1,7,0,6,5,3,
  5,7,3,2,6,0,4,1,
  6,3,7,1,5,4,0,2,
  7,5,6,4,3,1,2,0
};
__device__ __constant__ float c_Sg[64] = {
  1,1,1,1,-1,-1,-1,-1,
  1,1,-1,-1,1,-1,1,-1,
  1,1,1,-1,-1,1,1,1,
  1,1,1,1,-1,-1,-1,-1,
  1,1,-1,1,1,1,-1,1,
  1,1,1,-1,-1,1,1,1,
  1,1,-1,-1,1,-1,1,-1,
  1,1,-1,1,1,1,-1,1
};

__device__ inline unsigned short f2bf(float f) {  // RNE float->bf16
  unsigned int u = __float_as_uint(f);
  u += 0x7FFFu + ((u >> 16) & 1u);
  return (unsigned short)(u >> 16);
}

// ---------------- Prep A: x [8][128][128][128] f32 NCHW -> xt [8][130][130][128] bf16 NHWC (padded) ---
__global__ __launch_bounds__(256) void xpose_kernel(const float* __restrict__ x,
                                                    unsigned short* __restrict__ xt) {
  __shared__ unsigned short t[128 * 33];  // [ic][w], stride 33 to kill bank conflicts
  const int wt  = blockIdx.x;       // 0..3  (tile of 32 w)
  const int h   = blockIdx.y;       // 0..127
  const int b   = blockIdx.z;       // 0..7
  const int tid = threadIdx.x;
  const int w0  = wt * 32;
  const int wl  = tid & 31;
  const int ic0 = tid >> 5;         // 0..7
  #pragma unroll
  for (int i = 0; i < 16; ++i) {    // read coalesced along w
    int ic = ic0 + i * 8;
    float v = x[((size_t)(b * 128 + ic) * 128 + h) * 128 + w0 + wl];
    t[ic * 33 + wl] = f2bf(v);
  }
  __syncthreads();
  #pragma unroll
  for (int i = 0; i < 8; ++i) {     // write coalesced along ic
    int q = tid + i * 256;          // 0..2047 = 32 w * 64 ic-pairs
    int w = q >> 6;
    int p = q & 63;
    unsigned int lo = t[(2 * p) * 33 + w];
    unsigned int hi = t[(2 * p + 1) * 33 + w];
    size_t off = ((size_t)(b * 130 + h + 1) * 130 + (w0 + w + 1)) * 128 + 2 * p;
    *(unsigned int*)(xt + off) = lo | (hi << 16);
  }
}

// ---------------- Prep B (merged): blocks [0,576) build vt + beff; blocks [576,1608)
// zero the 1-pixel border of xt (interior fully overwritten by xpose).
// vt layout: vt[t][ks][ocb][lane][8] bf16 — per-wave B-fragment is one coalesced 1KB
// load: oc = ocb*16 + (lane&15), ic = ks*32 + (lane>>4)*8 + e.
__global__ __launch_bounds__(256) void prep_kernel(const float* __restrict__ W,
                                                   const float* __restrict__ bias,
                                                   unsigned short* __restrict__ vt,
                                                   float* __restrict__ beff,
                                                   unsigned short* __restrict__ xt) {
  const int bid = blockIdx.x;
  if (bid < 576) {
    int gid = bid * 256 + threadIdx.x;          // 9*128*128 = 147456 threads exactly
    int t   = gid >> 14;
    int rem = gid & 16383;
    int oc  = rem >> 7;
    int ic  = rem & 127;
    int m = oc & 7, cout = oc >> 3;
    int k = ic & 7, cin = ic >> 3;
    int j = c_J[m * 8 + k];
    float s = c_Sg[m * 8 + k];
    float val = s * W[((j * 16 + cout) * 16 + cin) * 9 + t];
    int ks = ic >> 5, quad = (ic >> 3) & 3, e = ic & 7;
    int ocb = oc >> 4, l15 = oc & 15;
    vt[(size_t)((t * 4 + ks) * 8 + ocb) * 512 + (quad * 16 + l15) * 8 + e] = f2bf(val);
    if (gid < 128) {
      int m2 = gid & 7, cout2 = gid >> 3;
      float acc = 0.f;
      #pragma unroll
      for (int kk = 0; kk < 8; ++kk)
        acc += c_Sg[m2 * 8 + kk] * bias[c_J[m2 * 8 + kk] * 16 + cout2];
      beff[gid] = acc;
    }
  } else {
    int g2 = (bid - 576) * 256 + threadIdx.x;   // 0..264191 = 8 b * 516 px * 64 uints
    int b  = g2 / 33024;
    int g  = g2 - b * 33024;
    const int p = g >> 6, u = g & 63;
    int h, w;
    if (p < 130)      { h = 0;       w = p; }
    else if (p < 260) { h = 129;     w = p - 130; }
    else if (p < 388) { h = p - 259; w = 0; }   // rows 1..128, col 0
    else              { h = p - 387; w = 129; } // rows 1..128, col 129
    *(unsigned int*)(xt + ((size_t)(b * 130 + h) * 130 + w) * 128 + 2 * u) = 0u;
  }
}

// ---------------- Main: tap-decomposed implicit GEMM, bf16 MFMA 16x16x32 ----------------
// Block: 256 thr = 4 waves. Per tile: 8 rows x 16 cols of output pixels x all 128 oc.
// Each block processes TWO h-tiles (by0 and by0+8); tile-1's 45KiB x-halo is
// global-loaded into registers before tile-0's compute (T14 issue-early / write-late),
// so its HBM/L2 latency hides under ~20us of MFMA.
// lds_x XOR-swizzled: 16B chunk c stored at c ^ ((c>>4)&7)  (row = c>>4 = hh*18+ww).
// B-fragments straight from global vt (L2-resident, coalesced 1KB/wave load).
// Grid 512 blocks = exactly 2 blocks/CU, all resident, zero ramp/tail.
__global__ __launch_bounds__(256) void conv_kernel(const unsigned short* __restrict__ xt,
                                                   const unsigned short* __restrict__ vt,
                                                   const float* __restrict__ beff,
                                                   float* __restrict__ out) {
  __shared__ __align__(16) unsigned short lds_x[10 * 18 * 128]; // halo [hh][ww][ic], 45 KiB
  const int tid  = threadIdx.x;
  const int bx   = blockIdx.x;    // 0..7   w tile (16)
  const int by0  = blockIdx.y;    // 0..7   h tile pair base (tiles by0, by0+8)
  const int b    = blockIdx.z;    // 0..7
  const int lane = tid & 63;
  const int wave = tid >> 6;
  const int wm   = wave >> 1;     // 0..1
  const int wn   = wave & 1;      // 0..1
  const int l15  = lane & 15;
  const int quad = lane >> 4;

  const unsigned short* xb0 = xt + ((size_t)(b * 130 + by0 * 8) * 130 + bx * 16) * 128;
  const unsigned short* xb1 = xb0 + (size_t)64 * 130 * 128;   // h-tile by0+8

  uint4 pre[12];
  // Stage tile-0 halo (rows by0*8..+9, cols bx*16..+17, 128 ic) = 2880 x 16B chunks,
  // swizzled on the write side.
  #pragma unroll
  for (int i = 0; i < 12; ++i) {
    int c = tid + i * 256;
    if (i < 11 || tid < 64) {
      int hh = c / 288;            // 288 chunks per halo row (18*128*2B/16B)
      int r  = c - hh * 288;
      pre[i] = *((const uint4*)(xb0 + (size_t)hh * (130 * 128)) + r);
    }
  }
  #pragma unroll
  for (int i = 0; i < 12; ++i) {
    int c = tid + i * 256;
    if (i < 11 || tid < 64)
      ((uint4*)lds_x)[c ^ ((c >> 4) & 7)] = pre[i];
  }
  __syncthreads();

  // T14 issue-early: tile-1 halo loads in flight during tile-0 compute.
  #pragma unroll
  for (int i = 0; i < 12; ++i) {
    int c = tid + i * 256;
    if (i < 11 || tid < 64) {
      int hh = c / 288;
      int r  = c - hh * 288;
      pre[i] = *((const uint4*)(xb1 + (size_t)hh * (130 * 128)) + r);
    }
  }

  const unsigned short* vtw = vt + (size_t)(wn * 4) * 512 + (size_t)lane * 8;

  #pragma unroll
  for (int tile = 0; tile < 2; ++tile) {
    f32x4 acc[4][4];
    #pragma unroll
    for (int mi = 0; mi < 4; ++mi)
      #pragma unroll
      for (int ni = 0; ni < 4; ++ni)
        acc[mi][ni] = f32x4{0.f, 0.f, 0.f, 0.f};

    #pragma unroll
    for (int t = 0; t < 9; ++t) {
      const int dh = t / 3, dw = t % 3;
      int rowb[4];
      #pragma unroll
      for (int mi = 0; mi < 4; ++mi)
        rowb[mi] = (wm * 4 + mi + dh) * 18 + l15 + dw;   // per-lane LDS row
      #pragma unroll
      for (int ks = 0; ks < 4; ++ks) {                   // K = 128 = 4 x 32
        short8 bb[4];
        #pragma unroll
        for (int ni = 0; ni < 4; ++ni)                   // coalesced 1KB wave load, L2 hit
          bb[ni] = *(const short8*)(vtw + (size_t)((t * 4 + ks) * 8 + ni) * 512);
        short8 a[4];
        #pragma unroll
        for (int mi = 0; mi < 4; ++mi) {
          int row = rowb[mi];
          int off = row * 256 + ((ks * 64 + quad * 16) ^ ((row & 7) << 4));  // swizzled read
          a[mi] = *(const short8*)((const char*)lds_x + off);
        }
        #pragma unroll
        for (int mi = 0; mi < 4; ++mi)
          #pragma unroll
          for (int ni = 0; ni < 4; ++ni)
            acc[mi][ni] = __builtin_amdgcn_mfma_f32_16x16x32_bf16(a[mi], bb[ni], acc[mi][ni], 0, 0, 0);
      }
    }

    // Epilogue: D row = quad*4+reg (pixel w offset), col = l15 (oc). float4, w-contiguous.
    const int h0 = by0 * 8 + tile * 64, w0 = bx * 16;
    #pragma unroll
    for (int ni = 0; ni < 4; ++ni) {
      int oc = (wn * 4 + ni) * 16 + l15;
      float bv = beff[oc];
      #pragma unroll
      for (int mi = 0; mi < 4; ++mi) {
        int h = h0 + wm * 4 + mi;
        int w = w0 + quad * 4;
        f32x4 v = acc[mi][ni];
        v[0] += bv; v[1] += bv; v[2] += bv; v[3] += bv;
        *(f32x4*)(out + ((size_t)(b * 128 + oc) * 128 + h) * 128 + w) = v;
      }
    }

    if (tile == 0) {
      __syncthreads();             // all waves done reading tile-0 LDS
      #pragma unroll
      for (int i = 0; i < 12; ++i) {   // T14 write-late: prefetched regs -> LDS
        int c = tid + i * 256;
        if (i < 11 || tid < 64)
          ((uint4*)lds_x)[c ^ ((c >> 4) & 7)] = pre[i];
      }
      __syncthreads();
    }
  }
}

extern "C" void kernel_launch(void* const* d_in, const int* in_sizes, int n_in,
                              void* d_out, int out_size, void* d_ws, size_t ws_size,
                              hipStream_t stream) {
  (void)in_sizes; (void)n_in; (void)out_size; (void)ws_size;
  const float* x    = (const float*)d_in[0];   // [8][128][128][128]
  const float* W    = (const float*)d_in[1];   // [8][16][16][3][3]
  const float* bias = (const float*)d_in[2];   // [8][16]
  float* out = (float*)d_out;                  // [8][128][128][128]

  const size_t XT_BYTES = (size_t)8 * 130 * 130 * 128 * 2;   // 34,611,200
  const size_t VT_BYTES = (size_t)9 * 4 * 8 * 512 * 2;       //    294,912
  unsigned short* xt = (unsigned short*)d_ws;
  unsigned short* vt = (unsigned short*)((char*)d_ws + XT_BYTES);
  float* beff = (float*)((char*)d_ws + XT_BYTES + VT_BYTES);

  prep_kernel<<<dim3(1608), 256, 0, stream>>>(W, bias, vt, beff, xt);  // vt+beff+border
  xpose_kernel<<<dim3(4, 128, 8), 256, 0, stream>>>(x, xt);
  conv_kernel<<<dim3(8, 8, 8), 256, 0, stream>>>(xt, vt, beff, out);
}

// Round 6
// 170.909 us; speedup vs baseline: 1.1237x; 1.1237x over previous
//
#include <hip/hip_runtime.h>
#include <stdint.h>
#include <stddef.h>

// GA3 conv2d == one dense 3x3 conv with sign-permuted weights:
//   out[b, c*8+m, h, w] = bias_eff[c*8+m]
//     + sum_{cin,k,kh,kw} s(m,k) * W[j(m,k),c,cin,kh,kw] * x[b, cin*8+k, h+kh-1, w+kw-1]
// bf16 MFMA implicit GEMM over 9 taps (K=128 each).
// R3 (2nd submit; prior run died to container-infra failure — OOB/alignment audit clean):
// revert R2's cross-tile prefetch (VGPR 240 + scratch spills, +60MB HBM).
// Back to R1 structure (1024 blocks, 4 waves, one barrier), with:
//  - wave split by h only: every wave covers 2 h-rows x 16 w x ALL 128 oc ->
//    all 4 waves load IDENTICAL B-fragments -> L1-resident B (~half latency),
//    and per-wave A ds_reads halve.
//  - s_setprio(1/0) around each MFMA burst (waves are independent post-stage).
//  - __launch_bounds__(256,3): VGPR cap ~168, guarantees 3 blocks/CU, no spill balloon.
// Carried: XOR-swizzled lds_x, B direct from L2/L1-resident vt, border-zero, merged prep.

typedef __attribute__((ext_vector_type(8))) short short8;   // 8 x bf16 (4 VGPRs)
typedef __attribute__((ext_vector_type(4))) float f32x4;    // MFMA accumulator

// j(m,k) and s(m,k): unique j with S[m,j,k]!=0, transcribed from _TERMS.
__device__ __constant__ int c_J[64] = {
  0,1,2,3,4,5,6,7,
  1,0,4,6,2,7,3,5,
  2,4,0,5,1,3,7,6,
  3,6,5,0,7,2,1,4,
  4,2,1,7,0,6,5,3,
  5,7,3,2,6,0,4,1,
  6,3,7,1,5,4,0,2,
  7,5,6,4,3,1,2,0
};
__device__ __constant__ float c_Sg[64] = {
  1,1,1,1,-1,-1,-1,-1,
  1,1,-1,-1,1,-1,1,-1,
  1,1,1,-1,-1,1,1,1,
  1,1,1,1,-1,-1,-1,-1,
  1,1,-1,1,1,1,-1,1,
  1,1,1,-1,-1,1,1,1,
  1,1,-1,-1,1,-1,1,-1,
  1,1,-1,1,1,1,-1,1
};

__device__ inline unsigned short f2bf(float f) {  // RNE float->bf16
  unsigned int u = __float_as_uint(f);
  u += 0x7FFFu + ((u >> 16) & 1u);
  return (unsigned short)(u >> 16);
}

// ---------------- Prep A: x [8][128][128][128] f32 NCHW -> xt [8][130][130][128] bf16 NHWC (padded) ---
__global__ __launch_bounds__(256) void xpose_kernel(const float* __restrict__ x,
                                                    unsigned short* __restrict__ xt) {
  __shared__ unsigned short t[128 * 33];  // [ic][w], stride 33 to kill bank conflicts
  const int wt  = blockIdx.x;       // 0..3  (tile of 32 w)
  const int h   = blockIdx.y;       // 0..127
  const int b   = blockIdx.z;       // 0..7
  const int tid = threadIdx.x;
  const int w0  = wt * 32;
  const int wl  = tid & 31;
  const int ic0 = tid >> 5;         // 0..7
  #pragma unroll
  for (int i = 0; i < 16; ++i) {    // read coalesced along w
    int ic = ic0 + i * 8;
    float v = x[((size_t)(b * 128 + ic) * 128 + h) * 128 + w0 + wl];
    t[ic * 33 + wl] = f2bf(v);
  }
  __syncthreads();
  #pragma unroll
  for (int i = 0; i < 8; ++i) {     // write coalesced along ic
    int q = tid + i * 256;          // 0..2047 = 32 w * 64 ic-pairs
    int w = q >> 6;
    int p = q & 63;
    unsigned int lo = t[(2 * p) * 33 + w];
    unsigned int hi = t[(2 * p + 1) * 33 + w];
    size_t off = ((size_t)(b * 130 + h + 1) * 130 + (w0 + w + 1)) * 128 + 2 * p;
    *(unsigned int*)(xt + off) = lo | (hi << 16);
  }
}

// ---------------- Prep B (merged): blocks [0,576) build vt + beff; blocks [576,1608)
// zero the 1-pixel border of xt (interior fully overwritten by xpose).
// vt layout: vt[t][ks][ocb][lane][8] bf16 — per-wave B-fragment is one coalesced 1KB
// load: oc = ocb*16 + (lane&15), ic = ks*32 + (lane>>4)*8 + e.
__global__ __launch_bounds__(256) void prep_kernel(const float* __restrict__ W,
                                                   const float* __restrict__ bias,
                                                   unsigned short* __restrict__ vt,
                                                   float* __restrict__ beff,
                                                   unsigned short* __restrict__ xt) {
  const int bid = blockIdx.x;
  if (bid < 576) {
    int gid = bid * 256 + threadIdx.x;          // 9*128*128 = 147456 threads exactly
    int t   = gid >> 14;
    int rem = gid & 16383;
    int oc  = rem >> 7;
    int ic  = rem & 127;
    int m = oc & 7, cout = oc >> 3;
    int k = ic & 7, cin = ic >> 3;
    int j = c_J[m * 8 + k];
    float s = c_Sg[m * 8 + k];
    float val = s * W[((j * 16 + cout) * 16 + cin) * 9 + t];
    int ks = ic >> 5, quad = (ic >> 3) & 3, e = ic & 7;
    int ocb = oc >> 4, l15 = oc & 15;
    vt[(size_t)((t * 4 + ks) * 8 + ocb) * 512 + (quad * 16 + l15) * 8 + e] = f2bf(val);
    if (gid < 128) {
      int m2 = gid & 7, cout2 = gid >> 3;
      float acc = 0.f;
      #pragma unroll
      for (int kk = 0; kk < 8; ++kk)
        acc += c_Sg[m2 * 8 + kk] * bias[c_J[m2 * 8 + kk] * 16 + cout2];
      beff[gid] = acc;
    }
  } else {
    int g2 = (bid - 576) * 256 + threadIdx.x;   // 0..264191 = 8 b * 516 px * 64 uints
    int b  = g2 / 33024;
    int g  = g2 - b * 33024;
    const int p = g >> 6, u = g & 63;
    int h, w;
    if (p < 130)      { h = 0;       w = p; }
    else if (p < 260) { h = 129;     w = p - 130; }
    else if (p < 388) { h = p - 259; w = 0; }   // rows 1..128, col 0
    else              { h = p - 387; w = 129; } // rows 1..128, col 129
    *(unsigned int*)(xt + ((size_t)(b * 130 + h) * 130 + w) * 128 + 2 * u) = 0u;
  }
}

// ---------------- Main: tap-decomposed implicit GEMM, bf16 MFMA 16x16x32 ----------------
// Block: 256 thr = 4 waves. Tile: 8 rows x 16 cols of output pixels x all 128 oc.
// Wave w owns h-rows {2w, 2w+1} x 16 w-px x ALL 128 oc: acc[2][8], and every wave's
// B-fragment addresses are identical -> L1-resident after first toucher.
// lds_x XOR-swizzled: 16B chunk c stored at c ^ ((c>>4)&7)  (row = c>>4 = hh*18+ww).
// Exactly ONE barrier per block; LDS 45KiB + VGPR<=168 -> 3 blocks/CU.
__global__ __launch_bounds__(256, 3) void conv_kernel(const unsigned short* __restrict__ xt,
                                                      const unsigned short* __restrict__ vt,
                                                      const float* __restrict__ beff,
                                                      float* __restrict__ out) {
  __shared__ __align__(16) unsigned short lds_x[10 * 18 * 128]; // halo [hh][ww][ic], 45 KiB
  const int tid  = threadIdx.x;
  const int bx   = blockIdx.x;    // 0..7   w tile (16)
  const int by   = blockIdx.y;    // 0..15  h tile (8)
  const int b    = blockIdx.z;    // 0..7
  const int lane = tid & 63;
  const int wave = tid >> 6;      // 0..3 -> h-rows 2*wave, 2*wave+1
  const int l15  = lane & 15;
  const int quad = lane >> 4;

  // Stage x halo tile (rows by*8..+9, cols bx*16..+17, 128 ic) = 2880 x 16B chunks,
  // swizzled on the write side.
  {
    const unsigned short* xb = xt + ((size_t)(b * 130 + by * 8) * 130 + bx * 16) * 128;
    #pragma unroll
    for (int i = 0; i < 11; ++i) {
      int c  = tid + i * 256;
      int hh = c / 288;            // 288 chunks per halo row (18*128*2B/16B)
      int r  = c - hh * 288;
      uint4 v = *((const uint4*)(xb + (size_t)hh * (130 * 128)) + r);
      ((uint4*)lds_x)[c ^ ((c >> 4) & 7)] = v;
    }
    if (tid < 64) {                // tail: chunks 2816..2879
      int c  = tid + 2816;
      int hh = c / 288;
      int r  = c - hh * 288;
      uint4 v = *((const uint4*)(xb + (size_t)hh * (130 * 128)) + r);
      ((uint4*)lds_x)[c ^ ((c >> 4) & 7)] = v;
    }
  }
  __syncthreads();                 // the only barrier

  f32x4 acc[2][8];
  #pragma unroll
  for (int mi = 0; mi < 2; ++mi)
    #pragma unroll
    for (int ni = 0; ni < 8; ++ni)
      acc[mi][ni] = f32x4{0.f, 0.f, 0.f, 0.f};

  const unsigned short* vtw = vt + (size_t)lane * 8;

  #pragma unroll
  for (int t = 0; t < 9; ++t) {
    const int dh = t / 3, dw = t % 3;
    int rowb[2];
    #pragma unroll
    for (int mi = 0; mi < 2; ++mi)
      rowb[mi] = (wave * 2 + mi + dh) * 18 + l15 + dw;   // per-lane LDS row
    #pragma unroll
    for (int ks = 0; ks < 4; ++ks) {                     // K = 128 = 4 x 32
      short8 bb[8];
      #pragma unroll
      for (int ni = 0; ni < 8; ++ni)   // identical across waves -> L1 hit after 1st
        bb[ni] = *(const short8*)(vtw + (size_t)((t * 4 + ks) * 8 + ni) * 512);
      short8 a[2];
      #pragma unroll
      for (int mi = 0; mi < 2; ++mi) {
        int row = rowb[mi];
        int off = row * 256 + ((ks * 64 + quad * 16) ^ ((row & 7) << 4));  // swizzled read
        a[mi] = *(const short8*)((const char*)lds_x + off);
      }
      __builtin_amdgcn_s_setprio(1);
      #pragma unroll
      for (int mi = 0; mi < 2; ++mi)
        #pragma unroll
        for (int ni = 0; ni < 8; ++ni)
          acc[mi][ni] = __builtin_amdgcn_mfma_f32_16x16x32_bf16(a[mi], bb[ni], acc[mi][ni], 0, 0, 0);
      __builtin_amdgcn_s_setprio(0);
    }
  }

  // Epilogue: D row = quad*4+reg (pixel w offset), col = l15 (oc). float4, w-contiguous.
  const int h0 = by * 8, w0 = bx * 16;
  #pragma unroll
  for (int ni = 0; ni < 8; ++ni) {
    int oc = ni * 16 + l15;
    float bv = beff[oc];
    #pragma unroll
    for (int mi = 0; mi < 2; ++mi) {
      int h = h0 + wave * 2 + mi;
      int w = w0 + quad * 4;
      f32x4 v = acc[mi][ni];
      v[0] += bv; v[1] += bv; v[2] += bv; v[3] += bv;
      *(f32x4*)(out + ((size_t)(b * 128 + oc) * 128 + h) * 128 + w) = v;
    }
  }
}

extern "C" void kernel_launch(void* const* d_in, const int* in_sizes, int n_in,
                              void* d_out, int out_size, void* d_ws, size_t ws_size,
                              hipStream_t stream) {
  (void)in_sizes; (void)n_in; (void)out_size; (void)ws_size;
  const float* x    = (const float*)d_in[0];   // [8][128][128][128]
  const float* W    = (const float*)d_in[1];   // [8][16][16][3][3]
  const float* bias = (const float*)d_in[2];   // [8][16]
  float* out = (float*)d_out;                  // [8][128][128][128]

  const size_t XT_BYTES = (size_t)8 * 130 * 130 * 128 * 2;   // 34,611,200
  const size_t VT_BYTES = (size_t)9 * 4 * 8 * 512 * 2;       //    294,912
  unsigned short* xt = (unsigned short*)d_ws;
  unsigned short* vt = (unsigned short*)((char*)d_ws + XT_BYTES);
  float* beff = (float*)((char*)d_ws + XT_BYTES + VT_BYTES);

  prep_kernel<<<dim3(1608), 256, 0, stream>>>(W, bias, vt, beff, xt);  // vt+beff+border
  xpose_kernel<<<dim3(4, 128, 8), 256, 0, stream>>>(x, xt);
  conv_kernel<<<dim3(8, 16, 8), 256, 0, stream>>>(xt, vt, beff, out);
}

// Round 7
// 153.913 us; speedup vs baseline: 1.2478x; 1.1104x over previous
//
#include <hip/hip_runtime.h>
#include <stdint.h>
#include <stddef.h>

// GA3 conv2d == one dense 3x3 conv with sign-permuted weights:
//   out[b, c*8+m, h, w] = bias_eff[c*8+m]
//     + sum_{cin,k,kh,kw} s(m,k) * W[j(m,k),c,cin,kh,kw] * x[b, cin*8+k, h+kh-1, w+kw-1]
// bf16 MFMA implicit GEMM over 9 taps (K=128 each).
// R4: conv reverted byte-identical to R1 (measured 49us; R3's h-split regressed to 66).
// New: xpose rewritten vectorized (float4 reads, uint2 writes, odd-stride LDS, whole
// 128-w row per block) -- old xpose was scalar 4B/lane both ways, est ~50us of the
// constant ~105us non-conv time. Border-zero folded into xpose; prep = vt+beff only.

typedef __attribute__((ext_vector_type(8))) short short8;   // 8 x bf16 (4 VGPRs)
typedef __attribute__((ext_vector_type(4))) float f32x4;    // MFMA accumulator

// j(m,k) and s(m,k): unique j with S[m,j,k]!=0, transcribed from _TERMS.
__device__ __constant__ int c_J[64] = {
  0,1,2,3,4,5,6,7,
  1,0,4,6,2,7,3,5,
  2,4,0,5,1,3,7,6,
  3,6,5,0,7,2,1,4,
  4,2,1,7,0,6,5,3,
  5,7,3,2,6,0,4,1,
  6,3,7,1,5,4,0,2,
  7,5,6,4,3,1,2,0
};
__device__ __constant__ float c_Sg[64] = {
  1,1,1,1,-1,-1,-1,-1,
  1,1,-1,-1,1,-1,1,-1,
  1,1,1,-1,-1,1,1,1,
  1,1,1,1,-1,-1,-1,-1,
  1,1,-1,1,1,1,-1,1,
  1,1,1,-1,-1,1,1,1,
  1,1,-1,-1,1,-1,1,-1,
  1,1,-1,1,1,1,-1,1
};

__device__ inline unsigned short f2bf(float f) {  // RNE float->bf16
  unsigned int u = __float_as_uint(f);
  u += 0x7FFFu + ((u >> 16) & 1u);
  return (unsigned short)(u >> 16);
}

// ---------------- Prep A: x [8][128][128][128] f32 NCHW -> xt [8][130][130][128] bf16 NHWC
// (padded). One block per (h, b): full 128-w row, all 128 ic.
// Reads: float4/lane, 512B contiguous per 32-lane group. Writes: uint2/lane, 512B/wave.
// LDS [ic][stride 129] -- odd stride => both access phases are 2-way (free, m136).
// Border zeroing folded in: col 0/129 every block; rows 0/129 in h==0/127 blocks.
__global__ __launch_bounds__(256) void xpose_kernel(const float* __restrict__ x,
                                                    unsigned short* __restrict__ xt) {
  __shared__ unsigned short t[128 * 129];   // 33,024 B
  const int h   = blockIdx.x;       // 0..127
  const int b   = blockIdx.y;       // 0..7
  const int tid = threadIdx.x;
  // Phase 1: global float4 -> bf16 -> LDS [ic][w]
  #pragma unroll
  for (int i = 0; i < 16; ++i) {
    int idx = tid + i * 256;        // 0..4095 = 128 ic * 32 w-quads
    int ic = idx >> 5, wq = idx & 31;
    const float4 v = *(const float4*)(x + ((size_t)(b * 128 + ic) * 128 + h) * 128 + 4 * wq);
    unsigned short* d = t + ic * 129 + 4 * wq;
    d[0] = f2bf(v.x); d[1] = f2bf(v.y); d[2] = f2bf(v.z); d[3] = f2bf(v.w);
  }
  // Border: cols 0 and 129 of this row (h+1)
  if (tid < 128) {
    int c = tid >> 6, u = tid & 63;
    *(unsigned int*)(xt + ((size_t)(b * 130 + h + 1) * 130 + c * 129) * 128 + 2 * u) = 0u;
  }
  // Border: rows 0 / 129 (only the h==0 / h==127 blocks)
  if (h == 0 || h == 127) {
    int row = (h == 0) ? 0 : 129;
    for (int i = 0; i < 33; ++i) {
      int idx = tid + i * 256;      // 130 px * 64 uints = 8320
      if (idx < 8320) {
        int w = idx >> 6, u = idx & 63;
        *(unsigned int*)(xt + ((size_t)(b * 130 + row) * 130 + w) * 128 + 2 * u) = 0u;
      }
    }
  }
  __syncthreads();
  // Phase 2: LDS -> global, ic-contiguous uint2 (4 ic per lane per iter)
  #pragma unroll
  for (int i = 0; i < 16; ++i) {
    int idx = tid + i * 256;        // 0..4095 = 128 w * 32 ic-quads
    int w = idx >> 5, p4 = idx & 31;
    unsigned int s0 = t[(4 * p4 + 0) * 129 + w];
    unsigned int s1 = t[(4 * p4 + 1) * 129 + w];
    unsigned int s2 = t[(4 * p4 + 2) * 129 + w];
    unsigned int s3 = t[(4 * p4 + 3) * 129 + w];
    uint2 o; o.x = s0 | (s1 << 16); o.y = s2 | (s3 << 16);
    *(uint2*)(xt + ((size_t)(b * 130 + h + 1) * 130 + (w + 1)) * 128 + 4 * p4) = o;
  }
}

// ---------------- Prep B: vt[t][ks][ocb][lane][8] bf16 — per-wave B-fragment is one
// coalesced 1KB load: oc = ocb*16 + (lane&15), ic = ks*32 + (lane>>4)*8 + e.
// Also bias_eff[128] f32.
__global__ __launch_bounds__(256) void prep_kernel(const float* __restrict__ W,
                                                   const float* __restrict__ bias,
                                                   unsigned short* __restrict__ vt,
                                                   float* __restrict__ beff) {
  int gid = blockIdx.x * 256 + threadIdx.x;   // 9*128*128 = 147456 threads exactly
  int t   = gid >> 14;
  int rem = gid & 16383;
  int oc  = rem >> 7;
  int ic  = rem & 127;
  int m = oc & 7, cout = oc >> 3;
  int k = ic & 7, cin = ic >> 3;
  int j = c_J[m * 8 + k];
  float s = c_Sg[m * 8 + k];
  float val = s * W[((j * 16 + cout) * 16 + cin) * 9 + t];
  int ks = ic >> 5, quad = (ic >> 3) & 3, e = ic & 7;
  int ocb = oc >> 4, l15 = oc & 15;
  vt[(size_t)((t * 4 + ks) * 8 + ocb) * 512 + (quad * 16 + l15) * 8 + e] = f2bf(val);
  if (gid < 128) {
    int m2 = gid & 7, cout2 = gid >> 3;
    float acc = 0.f;
    #pragma unroll
    for (int kk = 0; kk < 8; ++kk)
      acc += c_Sg[m2 * 8 + kk] * bias[c_J[m2 * 8 + kk] * 16 + cout2];
    beff[gid] = acc;
  }
}

// ---------------- Main: tap-decomposed implicit GEMM, bf16 MFMA 16x16x32 ----------------
// (byte-identical to the R1 kernel measured at 49us / MfmaUtil 30)
// Block: 256 thr = 4 waves. Tile: 8 rows x 16 cols of output pixels x all 128 oc.
// lds_x XOR-swizzled: 16B chunk c stored at c ^ ((c>>4)&7)  (row = c>>4 = hh*18+ww).
// B-fragments come straight from global vt (L2-resident, coalesced 1KB/wave load).
// Exactly ONE barrier per block; LDS 45KiB -> 3 blocks/CU.
__global__ __launch_bounds__(256) void conv_kernel(const unsigned short* __restrict__ xt,
                                                   const unsigned short* __restrict__ vt,
                                                   const float* __restrict__ beff,
                                                   float* __restrict__ out) {
  __shared__ __align__(16) unsigned short lds_x[10 * 18 * 128]; // halo [hh][ww][ic], 45 KiB
  const int tid  = threadIdx.x;
  const int bx   = blockIdx.x;    // 0..7   w tile (16)
  const int by   = blockIdx.y;    // 0..15  h tile (8)
  const int b    = blockIdx.z;    // 0..7
  const int lane = tid & 63;
  const int wave = tid >> 6;
  const int wm   = wave >> 1;     // 0..1
  const int wn   = wave & 1;      // 0..1
  const int l15  = lane & 15;
  const int quad = lane >> 4;

  // Stage x halo tile (rows by*8..+9, cols bx*16..+17, 128 ic) = 2880 x 16B chunks,
  // swizzled on the write side.
  {
    const unsigned short* xb = xt + ((size_t)(b * 130 + by * 8) * 130 + bx * 16) * 128;
    #pragma unroll
    for (int i = 0; i < 11; ++i) {
      int c  = tid + i * 256;
      int hh = c / 288;            // 288 chunks per halo row (18*128*2B/16B)
      int r  = c - hh * 288;
      uint4 v = *((const uint4*)(xb + (size_t)hh * (130 * 128)) + r);
      ((uint4*)lds_x)[c ^ ((c >> 4) & 7)] = v;
    }
    if (tid < 64) {                // tail: chunks 2816..2879
      int c  = tid + 2816;
      int hh = c / 288;
      int r  = c - hh * 288;
      uint4 v = *((const uint4*)(xb + (size_t)hh * (130 * 128)) + r);
      ((uint4*)lds_x)[c ^ ((c >> 4) & 7)] = v;
    }
  }
  __syncthreads();                 // the only barrier

  f32x4 acc[4][4];
  #pragma unroll
  for (int mi = 0; mi < 4; ++mi)
    #pragma unroll
    for (int ni = 0; ni < 4; ++ni)
      acc[mi][ni] = f32x4{0.f, 0.f, 0.f, 0.f};

  const unsigned short* vtw = vt + (size_t)(wn * 4) * 512 + (size_t)lane * 8;

  #pragma unroll
  for (int t = 0; t < 9; ++t) {
    const int dh = t / 3, dw = t % 3;
    int rowb[4];
    #pragma unroll
    for (int mi = 0; mi < 4; ++mi)
      rowb[mi] = (wm * 4 + mi + dh) * 18 + l15 + dw;   // per-lane LDS row
    #pragma unroll
    for (int ks = 0; ks < 4; ++ks) {                   // K = 128 = 4 x 32
      short8 bb[4];
      #pragma unroll
      for (int ni = 0; ni < 4; ++ni)                   // coalesced 1KB wave load, L1/L2 hit
        bb[ni] = *(const short8*)(vtw + (size_t)((t * 4 + ks) * 8 + ni) * 512);
      short8 a[4];
      #pragma unroll
      for (int mi = 0; mi < 4; ++mi) {
        int row = rowb[mi];
        int off = row * 256 + ((ks * 64 + quad * 16) ^ ((row & 7) << 4));  // swizzled read
        a[mi] = *(const short8*)((const char*)lds_x + off);
      }
      #pragma unroll
      for (int mi = 0; mi < 4; ++mi)
        #pragma unroll
        for (int ni = 0; ni < 4; ++ni)
          acc[mi][ni] = __builtin_amdgcn_mfma_f32_16x16x32_bf16(a[mi], bb[ni], acc[mi][ni], 0, 0, 0);
    }
  }

  // Epilogue: D row = quad*4+reg (pixel w offset), col = l15 (oc). float4 stores, w-contiguous.
  const int h0 = by * 8, w0 = bx * 16;
  #pragma unroll
  for (int ni = 0; ni < 4; ++ni) {
    int oc = (wn * 4 + ni) * 16 + l15;
    float bv = beff[oc];
    #pragma unroll
    for (int mi = 0; mi < 4; ++mi) {
      int h = h0 + wm * 4 + mi;
      int w = w0 + quad * 4;
      f32x4 v = acc[mi][ni];
      v[0] += bv; v[1] += bv; v[2] += bv; v[3] += bv;
      *(f32x4*)(out + ((size_t)(b * 128 + oc) * 128 + h) * 128 + w) = v;
    }
  }
}

extern "C" void kernel_launch(void* const* d_in, const int* in_sizes, int n_in,
                              void* d_out, int out_size, void* d_ws, size_t ws_size,
                              hipStream_t stream) {
  (void)in_sizes; (void)n_in; (void)out_size; (void)ws_size;
  const float* x    = (const float*)d_in[0];   // [8][128][128][128]
  const float* W    = (const float*)d_in[1];   // [8][16][16][3][3]
  const float* bias = (const float*)d_in[2];   // [8][16]
  float* out = (float*)d_out;                  // [8][128][128][128]

  const size_t XT_BYTES = (size_t)8 * 130 * 130 * 128 * 2;   // 34,611,200
  const size_t VT_BYTES = (size_t)9 * 4 * 8 * 512 * 2;       //    294,912
  unsigned short* xt = (unsigned short*)d_ws;
  unsigned short* vt = (unsigned short*)((char*)d_ws + XT_BYTES);
  float* beff = (float*)((char*)d_ws + XT_BYTES + VT_BYTES);

  prep_kernel<<<dim3(576), 256, 0, stream>>>(W, bias, vt, beff);       // vt + beff
  xpose_kernel<<<dim3(128, 8), 256, 0, stream>>>(x, xt);               // incl. border zero
  conv_kernel<<<dim3(8, 16, 8), 256, 0, stream>>>(xt, vt, beff, out);
}